// Round 10
// baseline (2879.036 us; speedup 1.0000x reference)
//
#include <hip/hip_runtime.h>
#include <hip/hip_bf16.h>
#include <cstddef>

#define NN_   32768
#define DEG_  16
#define D1_   128
#define D2_   256
#define G_    64
#define DREP_ 128

typedef __attribute__((ext_vector_type(8))) short bf16x8;
typedef __attribute__((ext_vector_type(4))) float f32x4;
typedef __attribute__((ext_vector_type(4))) unsigned short us4;
typedef unsigned short ushort_t;

// ---------------------------------------------------------------------------
// Static device scratch (module-load allocated; every element read is written
// earlier in the same kernel_launch call).
// ---------------------------------------------------------------------------
__device__ __attribute__((aligned(16))) ushort_t g_feat1[(size_t)NN_ * D1_];   // in_feat bf16
__device__ __attribute__((aligned(16))) ushort_t g_hfeat[(size_t)NN_ * D2_];   // layer-1 out bf16
__device__ __attribute__((aligned(16))) ushort_t g_hB[(size_t)NN_ * D2_];      // final h per layer
__device__ __attribute__((aligned(16))) ushort_t g_P[(size_t)NN_ * 1024];      // bf16 proj table
__device__ __attribute__((aligned(16))) float    g_outh[(size_t)NN_ * D2_];
__device__ __attribute__((aligned(16))) ushort_t g_wih1[512 * 128];
__device__ __attribute__((aligned(16))) ushort_t g_whh1[512 * 128];
__device__ __attribute__((aligned(16))) ushort_t g_wself1[256 * 128];   // [N][K]
__device__ __attribute__((aligned(16))) ushort_t g_wneigh1[256 * 128];  // [N][K]
__device__ __attribute__((aligned(16))) ushort_t g_wih2[1024 * 256];
__device__ __attribute__((aligned(16))) ushort_t g_whh2[1024 * 256];
__device__ __attribute__((aligned(16))) ushort_t g_wself2[256 * 256];
__device__ __attribute__((aligned(16))) ushort_t g_wneigh2[256 * 256];
__device__ float g_gsum[G_ * D2_];
__device__ int   g_gcnt[G_];

// ---------------------------------------------------------------------------
__device__ __forceinline__ ushort_t f2bf(float f) {
    unsigned int u = __float_as_uint(f);
    u += 0x7fffu + ((u >> 16) & 1u);          // round-to-nearest-even
    return (ushort_t)(u >> 16);
}
__device__ __forceinline__ float bf2f(ushort_t u) {
    return __uint_as_float(((unsigned int)u) << 16);
}
__device__ __forceinline__ float sigf(float x) { return 1.f / (1.f + __expf(-x)); }
__device__ __forceinline__ float tanhf_(float x) { return 1.f - 2.f / (__expf(2.f * x) + 1.f); }

// ---------------------------------------------------------------------------
__global__ __launch_bounds__(256) void cvt_bf16(const float* __restrict__ src,
                                                ushort_t* __restrict__ dst, int n)
{
    int i = blockIdx.x * 256 + threadIdx.x;
    if (i < n) dst[i] = f2bf(src[i]);
}

// src [K][N] row-major -> dst [N][K] bf16
__global__ __launch_bounds__(256) void cvt_bf16_T(const float* __restrict__ src,
                                                  ushort_t* __restrict__ dst, int K, int N)
{
    int i = blockIdx.x * 256 + threadIdx.x;
    if (i < K * N) {
        int k = i / N, n = i % N;
        dst[n * K + k] = f2bf(src[i]);
    }
}

// ---------------------------------------------------------------------------
// Generic MFMA GEMM:  C[M,N] = act( A1@B1^T (+ A2@B2^T) (+bias) )
// A: [M][K] bf16;  B: [N][K] bf16.  Tile 64x64, BK=64, 256 threads / 4 waves.
// ---------------------------------------------------------------------------
template<bool DUAL, bool HAS_BIAS, bool RELU, bool OUTBF>
__global__ __launch_bounds__(256) void gemm_mfma(
    const ushort_t* __restrict__ A1, const ushort_t* __restrict__ B1,
    const ushort_t* __restrict__ A2, const ushort_t* __restrict__ B2,
    const float* __restrict__ bias, float* __restrict__ Cf,
    ushort_t* __restrict__ Cb, int M, int N, int K)
{
    __shared__ ushort_t As[64][72];
    __shared__ ushort_t Bs[64][72];
    const int tid = threadIdx.x;
    const int l = tid & 63, w = tid >> 6;
    const int m0 = blockIdx.y * 64, n0 = blockIdx.x * 64;

    f32x4 acc[4];
#pragma unroll
    for (int m = 0; m < 4; ++m) acc[m] = (f32x4){0.f, 0.f, 0.f, 0.f};

    const int npass = DUAL ? 2 : 1;
    for (int pass = 0; pass < npass; ++pass) {
        const ushort_t* __restrict__ A = (DUAL && pass) ? A2 : A1;
        const ushort_t* __restrict__ B = (DUAL && pass) ? B2 : B1;
        for (int k0 = 0; k0 < K; k0 += 64) {
#pragma unroll
            for (int i = 0; i < 2; ++i) {
                int cid = tid + 256 * i;
                int row = cid >> 3, col = (cid & 7) * 8;
                *(uint4*)&As[row][col] = *(const uint4*)&A[(size_t)(m0 + row) * K + k0 + col];
                *(uint4*)&Bs[row][col] = *(const uint4*)&B[(size_t)(n0 + row) * K + k0 + col];
            }
            __syncthreads();
#pragma unroll
            for (int kk = 0; kk < 64; kk += 32) {
                bf16x8 b = *(const bf16x8*)&Bs[16 * w + (l & 15)][kk + (l >> 4) * 8];
#pragma unroll
                for (int m = 0; m < 4; ++m) {
                    bf16x8 a = *(const bf16x8*)&As[16 * m + (l & 15)][kk + (l >> 4) * 8];
                    acc[m] = __builtin_amdgcn_mfma_f32_16x16x32_bf16(a, b, acc[m], 0, 0, 0);
                }
            }
            __syncthreads();
        }
    }

#pragma unroll
    for (int m = 0; m < 4; ++m) {
#pragma unroll
        for (int r = 0; r < 4; ++r) {
            int row = m0 + 16 * m + (l >> 4) * 4 + r;
            int col = n0 + 16 * w + (l & 15);
            float v = acc[m][r];
            if (HAS_BIAS) v += bias[col];
            if (RELU) v = fmaxf(v, 0.f);
            if (OUTBF) Cb[(size_t)row * N + col] = f2bf(v);
            else       Cf[(size_t)row * N + col] = v;
        }
    }
}

// ---------------------------------------------------------------------------
// Persistent self-contained LSTM: one block owns 32 nodes for ALL 16 steps.
// The recurrence only touches P[nbr] (constant) and the block's OWN h/c, so
// no cross-block sync is needed. h double-buffered in LDS, c in LDS (both
// padded +8 -> 528B row stride -> 2-way bank aliasing = free). One
// __syncthreads per step. whh fragments straight from L2; P gathered early
// per unit (8B vectors) to hide under MFMA.
// 256 thr / 4 waves. Per unit (64-dim slice d0): wave w owns dims
// [d0+16w, d0+16w+16), node-tiles nt in {0,1}. acc layout (verified rounds
// 8): col=lane&15 -> node, row=(lane>>4)*4+r -> 4 consecutive gate-dims.
// grid = NN/32 = 1024 blocks. LDS 52.7KB -> 3 blocks/CU.
// ---------------------------------------------------------------------------
template<int D>
__global__ __launch_bounds__(256, 3) void lstm_persist2(
    const ushort_t* __restrict__ whh,   // [4D][D] bf16
    const ushort_t* __restrict__ P,     // [NN][4D] bf16
    const int* __restrict__ nbr,
    ushort_t* __restrict__ h_out)       // [NN][D] bf16 (final h)
{
    constexpr int HP = D + 8;
    constexpr int KC = D / 32;
    constexpr int NU = D / 64;          // dim-slice units per step
    __shared__ ushort_t h_lds[2][32][HP];
    __shared__ ushort_t c_lds[32][HP];
    __shared__ int      nbr_lds[32][DEG_];

    const int tid = threadIdx.x;
    const int l = tid & 63, w = tid >> 6;
    const int lr = l & 15, lg = l >> 4;
    const int n0 = blockIdx.x * 32;

    // preload this block's neighbor table (32 x 16 ints)
    for (int i = tid; i < 32 * DEG_; i += 256)
        nbr_lds[i >> 4][i & 15] = nbr[(size_t)(n0 + (i >> 4)) * DEG_ + (i & 15)];
    __syncthreads();

    for (int t = 0; t < DEG_; ++t) {
        const int rb = t & 1, wb = rb ^ 1;   // t=0 writes buf 1; final h in buf 0

#pragma unroll
        for (int u = 0; u < NU; ++u) {
            const int d0 = u * 64;
            const int dd = d0 + w * 16 + lg * 4;     // this lane's 4 out-dims

            // early gather: neighbor ids + P rows (8B per gate per node-tile)
            int js[2];
#pragma unroll
            for (int nt = 0; nt < 2; ++nt)
                js[nt] = nbr_lds[nt * 16 + lr][t];

            us4 pg[2][4];
#pragma unroll
            for (int nt = 0; nt < 2; ++nt) {
                size_t base = (size_t)js[nt] * (4 * D) + dd;
#pragma unroll
                for (int g = 0; g < 4; ++g)
                    pg[nt][g] = *(const us4*)&P[base + g * D];
            }

            f32x4 acc[4][2];
#pragma unroll
            for (int g = 0; g < 4; ++g)
#pragma unroll
                for (int nt = 0; nt < 2; ++nt) acc[g][nt] = (f32x4){0.f, 0.f, 0.f, 0.f};

            if (t > 0) {
#pragma unroll
                for (int kc = 0; kc < KC; ++kc) {
                    const int k0 = kc * 32;
                    bf16x8 a[4];
#pragma unroll
                    for (int g = 0; g < 4; ++g)
                        a[g] = *(const bf16x8*)&whh[(size_t)(g * D + d0 + w * 16 + lr) * D + k0 + lg * 8];
                    bf16x8 b[2];
#pragma unroll
                    for (int nt = 0; nt < 2; ++nt)
                        b[nt] = *(const bf16x8*)&h_lds[rb][nt * 16 + lr][k0 + lg * 8];
#pragma unroll
                    for (int g = 0; g < 4; ++g)
#pragma unroll
                        for (int nt = 0; nt < 2; ++nt)
                            acc[g][nt] = __builtin_amdgcn_mfma_f32_16x16x32_bf16(
                                a[g], b[nt], acc[g][nt], 0, 0, 0);
                }
            }

            // cell update; c/h live in LDS (same-wave ownership of c slice)
#pragma unroll
            for (int nt = 0; nt < 2; ++nt) {
                const int node = nt * 16 + lr;
                us4 cold = (t > 0) ? *(const us4*)&c_lds[node][dd]
                                   : (us4){0, 0, 0, 0};
                us4 cnew, hnew;
#pragma unroll
                for (int r = 0; r < 4; ++r) {
                    float gi = acc[0][nt][r] + bf2f(pg[nt][0][r]);
                    float gf = acc[1][nt][r] + bf2f(pg[nt][1][r]);
                    float gg = acc[2][nt][r] + bf2f(pg[nt][2][r]);
                    float go = acc[3][nt][r] + bf2f(pg[nt][3][r]);
                    float cp = (t > 0) ? bf2f(cold[r]) : 0.f;
                    float cn = sigf(gf) * cp + sigf(gi) * tanhf_(gg);
                    cnew[r] = f2bf(cn);
                    hnew[r] = f2bf(sigf(go) * tanhf_(cn));
                }
                *(us4*)&c_lds[node][dd] = cnew;
                *(us4*)&h_lds[wb][node][dd] = hnew;
            }
        }
        __syncthreads();   // all h_lds[wb] writes visible; rb free for reuse
    }

    // final h is in h_lds[0] (DEG_ even). Coalesced 16B global write.
    constexpr int CH = 32 * D / 8;
#pragma unroll
    for (int cid = tid; cid < CH; cid += 256) {
        int row = cid / (D / 8), cc = (cid % (D / 8)) * 8;
        *(bf16x8*)&h_out[(size_t)(n0 + row) * D + cc] = *(const bf16x8*)&h_lds[0][row][cc];
    }
}

// ---------------------------------------------------------------------------
__global__ void graph_counts(const int* __restrict__ n2g, int* __restrict__ cnt)
{
    __shared__ int lb[G_ + 1];
    int g = threadIdx.x;
    if (g <= G_) {
        int lo = 0, hi = NN_;
        while (lo < hi) {
            int mid = (lo + hi) >> 1;
            if (n2g[mid] < g) lo = mid + 1; else hi = mid;
        }
        lb[g] = lo;
    }
    __syncthreads();
    if (g < G_) cnt[g] = lb[g + 1] - lb[g];
}

// 64-node chunks -> 512 blocks.
__global__ __launch_bounds__(256) void seg_sum(
    const float* __restrict__ X, const int* __restrict__ n2g,
    float* __restrict__ gsum)
{
    int d = threadIdx.x;
    int n_start = blockIdx.x * 64;
    int cur = n2g[n_start];
    float acc = 0.f;
    for (int n = n_start; n < n_start + 64; ++n) {
        int g = n2g[n];
        if (g != cur) {
            atomicAdd(&gsum[cur * D2_ + d], acc);
            acc = 0.f;
            cur = g;
        }
        acc += X[(size_t)n * D2_ + d];
    }
    atomicAdd(&gsum[cur * D2_ + d], acc);
}

__global__ __launch_bounds__(128) void head_kernel(
    const float* __restrict__ gsum, const int* __restrict__ cnt,
    const float* __restrict__ w_mu, const float* __restrict__ b_mu,
    const float* __restrict__ w_sig, const float* __restrict__ b_sig,
    float* __restrict__ out)
{
    __shared__ float x[D2_];
    int g = blockIdx.x, j = threadIdx.x;
    float inv = 1.f / fmaxf((float)cnt[g], 1.f);
    x[j] = gsum[g * D2_ + j] * inv;
    x[j + 128] = gsum[g * D2_ + 128 + j] * inv;
    __syncthreads();
    float mu = b_mu[j], sg = b_sig[j];
    for (int k = 0; k < D2_; ++k) {
        float xv = x[k];
        mu += xv * w_mu[k * DREP_ + j];
        sg += xv * w_sig[k * DREP_ + j];
    }
    out[g * DREP_ + j] = mu;
    out[G_ * DREP_ + g * DREP_ + j] = sg;
}

// ---------------------------------------------------------------------------
extern "C" void kernel_launch(void* const* d_in, const int* in_sizes, int n_in,
                              void* d_out, int out_size, void* d_ws, size_t ws_size,
                              hipStream_t stream)
{
    const float* in_feat   = (const float*)d_in[0];
    const int*   neighbors = (const int*)d_in[1];
    const int*   node2graph= (const int*)d_in[2];
    const float* w_ih1     = (const float*)d_in[3];
    const float* w_hh1     = (const float*)d_in[4];
    const float* b_lstm1   = (const float*)d_in[5];
    const float* w_self1   = (const float*)d_in[6];
    const float* w_neigh1  = (const float*)d_in[7];
    const float* b1        = (const float*)d_in[8];
    const float* w_ih2     = (const float*)d_in[9];
    const float* w_hh2     = (const float*)d_in[10];
    const float* b_lstm2   = (const float*)d_in[11];
    const float* w_self2   = (const float*)d_in[12];
    const float* w_neigh2  = (const float*)d_in[13];
    const float* b2        = (const float*)d_in[14];
    const float* w_mu      = (const float*)d_in[15];
    const float* b_mu      = (const float*)d_in[16];
    const float* w_sigma   = (const float*)d_in[17];
    const float* b_sigma   = (const float*)d_in[18];

    void *pF1, *pHF, *pHB, *pP, *pOH;
    void *pWI1, *pWH1, *pWS1, *pWN1, *pWI2, *pWH2, *pWS2, *pWN2, *pGS, *pGC;
    hipGetSymbolAddress(&pF1, HIP_SYMBOL(g_feat1));
    hipGetSymbolAddress(&pHF, HIP_SYMBOL(g_hfeat));
    hipGetSymbolAddress(&pHB, HIP_SYMBOL(g_hB));
    hipGetSymbolAddress(&pP,  HIP_SYMBOL(g_P));
    hipGetSymbolAddress(&pOH, HIP_SYMBOL(g_outh));
    hipGetSymbolAddress(&pWI1, HIP_SYMBOL(g_wih1));
    hipGetSymbolAddress(&pWH1, HIP_SYMBOL(g_whh1));
    hipGetSymbolAddress(&pWS1, HIP_SYMBOL(g_wself1));
    hipGetSymbolAddress(&pWN1, HIP_SYMBOL(g_wneigh1));
    hipGetSymbolAddress(&pWI2, HIP_SYMBOL(g_wih2));
    hipGetSymbolAddress(&pWH2, HIP_SYMBOL(g_whh2));
    hipGetSymbolAddress(&pWS2, HIP_SYMBOL(g_wself2));
    hipGetSymbolAddress(&pWN2, HIP_SYMBOL(g_wneigh2));
    hipGetSymbolAddress(&pGS, HIP_SYMBOL(g_gsum));
    hipGetSymbolAddress(&pGC, HIP_SYMBOL(g_gcnt));

    ushort_t* feat1 = (ushort_t*)pF1;
    ushort_t* hfeat = (ushort_t*)pHF;
    ushort_t* hB    = (ushort_t*)pHB;
    ushort_t* P     = (ushort_t*)pP;
    float*    outh  = (float*)pOH;
    ushort_t* wih1  = (ushort_t*)pWI1;
    ushort_t* whh1  = (ushort_t*)pWH1;
    ushort_t* wself1= (ushort_t*)pWS1;
    ushort_t* wneigh1=(ushort_t*)pWN1;
    ushort_t* wih2  = (ushort_t*)pWI2;
    ushort_t* whh2  = (ushort_t*)pWH2;
    ushort_t* wself2= (ushort_t*)pWS2;
    ushort_t* wneigh2=(ushort_t*)pWN2;
    float*    gsum  = (float*)pGS;
    int*      gcnt  = (int*)pGC;

    // ---- Conversions ----
    cvt_bf16<<<(NN_ * D1_ + 255) / 256, 256, 0, stream>>>(in_feat, feat1, NN_ * D1_);
    cvt_bf16<<<(512 * 128 + 255) / 256, 256, 0, stream>>>(w_ih1, wih1, 512 * 128);
    cvt_bf16<<<(512 * 128 + 255) / 256, 256, 0, stream>>>(w_hh1, whh1, 512 * 128);
    cvt_bf16_T<<<(128 * 256 + 255) / 256, 256, 0, stream>>>(w_self1, wself1, 128, 256);
    cvt_bf16_T<<<(128 * 256 + 255) / 256, 256, 0, stream>>>(w_neigh1, wneigh1, 128, 256);
    cvt_bf16<<<(1024 * 256 + 255) / 256, 256, 0, stream>>>(w_ih2, wih2, 1024 * 256);
    cvt_bf16<<<(1024 * 256 + 255) / 256, 256, 0, stream>>>(w_hh2, whh2, 1024 * 256);
    cvt_bf16_T<<<(256 * 256 + 255) / 256, 256, 0, stream>>>(w_self2, wself2, 256, 256);
    cvt_bf16_T<<<(256 * 256 + 255) / 256, 256, 0, stream>>>(w_neigh2, wneigh2, 256, 256);

    // ---- Layer 1 ----
    // P1 = feat1 @ wih1^T + b_lstm1   [NN,512] -> bf16
    gemm_mfma<false, true, false, true>
        <<<dim3(512 / 64, NN_ / 64), 256, 0, stream>>>(
            feat1, wih1, nullptr, nullptr, b_lstm1, nullptr, P, NN_, 512, D1_);

    lstm_persist2<D1_><<<NN_ / 32, 256, 0, stream>>>(whh1, P, neighbors, hB);

    // hfeat = relu(feat1@wself1^T + hB@wneigh1^T + b1) -> bf16 [NN,256]
    gemm_mfma<true, true, true, true>
        <<<dim3(256 / 64, NN_ / 64), 256, 0, stream>>>(
            feat1, wself1, hB, wneigh1, b1, nullptr, hfeat, NN_, D2_, D1_);

    // ---- Layer 2 ----
    gemm_mfma<false, true, false, true>
        <<<dim3(1024 / 64, NN_ / 64), 256, 0, stream>>>(
            hfeat, wih2, nullptr, nullptr, b_lstm2, nullptr, P, NN_, 1024, D2_);

    lstm_persist2<D2_><<<NN_ / 32, 256, 0, stream>>>(whh2, P, neighbors, hB);

    // outh = hfeat@wself2^T + hB@wneigh2^T + b2   [NN,256] fp32
    gemm_mfma<true, true, false, false>
        <<<dim3(256 / 64, NN_ / 64), 256, 0, stream>>>(
            hfeat, wself2, hB, wneigh2, b2, outh, nullptr, NN_, D2_, D2_);

    // ---- Readout ----
    hipMemsetAsync(gsum, 0, (size_t)G_ * D2_ * sizeof(float), stream);
    graph_counts<<<1, 128, 0, stream>>>(node2graph, gcnt);
    seg_sum<<<NN_ / 64, 256, 0, stream>>>(outh, node2graph, gsum);
    head_kernel<<<G_, 128, 0, stream>>>(gsum, gcnt, w_mu, b_mu, w_sigma, b_sigma,
                                        (float*)d_out);
}

// Round 11
// 1464.536 us; speedup vs baseline: 1.9658x; 1.9658x over previous
//
#include <hip/hip_runtime.h>
#include <hip/hip_bf16.h>
#include <cstddef>

#define NN_   32768
#define DEG_  16
#define D1_   128
#define D2_   256
#define G_    64
#define DREP_ 128

typedef __attribute__((ext_vector_type(8))) short bf16x8;
typedef __attribute__((ext_vector_type(4))) float f32x4;
typedef __attribute__((ext_vector_type(4))) unsigned short us4;
typedef unsigned short ushort_t;

// ---------------------------------------------------------------------------
// Static device scratch (module-load allocated; every element read is written
// earlier in the same kernel_launch call).
// ---------------------------------------------------------------------------
__device__ __attribute__((aligned(16))) ushort_t g_feat1[(size_t)NN_ * D1_];   // in_feat bf16
__device__ __attribute__((aligned(16))) ushort_t g_hfeat[(size_t)NN_ * D2_];   // layer-1 out bf16
__device__ __attribute__((aligned(16))) ushort_t g_hA[(size_t)NN_ * D2_];      // h ping
__device__ __attribute__((aligned(16))) ushort_t g_hB[(size_t)NN_ * D2_];      // h pong
__device__ __attribute__((aligned(16))) ushort_t g_c[(size_t)NN_ * D2_];       // c state bf16
__device__ __attribute__((aligned(16))) ushort_t g_P[(size_t)NN_ * 1024];      // bf16 proj table
__device__ __attribute__((aligned(16))) float    g_outh[(size_t)NN_ * D2_];
__device__ __attribute__((aligned(16))) ushort_t g_wih1[512 * 128];
__device__ __attribute__((aligned(16))) ushort_t g_whh1[512 * 128];
__device__ __attribute__((aligned(16))) ushort_t g_wself1[256 * 128];   // [N][K]
__device__ __attribute__((aligned(16))) ushort_t g_wneigh1[256 * 128];  // [N][K]
__device__ __attribute__((aligned(16))) ushort_t g_wih2[1024 * 256];
__device__ __attribute__((aligned(16))) ushort_t g_whh2[1024 * 256];
__device__ __attribute__((aligned(16))) ushort_t g_wself2[256 * 256];
__device__ __attribute__((aligned(16))) ushort_t g_wneigh2[256 * 256];
__device__ float g_gsum[G_ * D2_];
__device__ int   g_gcnt[G_];

// ---------------------------------------------------------------------------
__device__ __forceinline__ ushort_t f2bf(float f) {
    unsigned int u = __float_as_uint(f);
    u += 0x7fffu + ((u >> 16) & 1u);          // round-to-nearest-even
    return (ushort_t)(u >> 16);
}
__device__ __forceinline__ float bf2f(ushort_t u) {
    return __uint_as_float(((unsigned int)u) << 16);
}
__device__ __forceinline__ float sigf(float x) { return 1.f / (1.f + __expf(-x)); }
__device__ __forceinline__ float tanhf_(float x) { return 1.f - 2.f / (__expf(2.f * x) + 1.f); }

// ---------------------------------------------------------------------------
__global__ __launch_bounds__(256) void cvt_bf16(const float* __restrict__ src,
                                                ushort_t* __restrict__ dst, int n)
{
    int i = blockIdx.x * 256 + threadIdx.x;
    if (i < n) dst[i] = f2bf(src[i]);
}

// src [K][N] row-major -> dst [N][K] bf16
__global__ __launch_bounds__(256) void cvt_bf16_T(const float* __restrict__ src,
                                                  ushort_t* __restrict__ dst, int K, int N)
{
    int i = blockIdx.x * 256 + threadIdx.x;
    if (i < K * N) {
        int k = i / N, n = i % N;
        dst[n * K + k] = f2bf(src[i]);
    }
}

// ---------------------------------------------------------------------------
// Generic MFMA GEMM:  C[M,N] = act( A1@B1^T (+ A2@B2^T) (+bias) )
// A: [M][K] bf16;  B: [N][K] bf16.  Tile 64x64, BK=64, 256 threads / 4 waves.
// ---------------------------------------------------------------------------
template<bool DUAL, bool HAS_BIAS, bool RELU, bool OUTBF>
__global__ __launch_bounds__(256) void gemm_mfma(
    const ushort_t* __restrict__ A1, const ushort_t* __restrict__ B1,
    const ushort_t* __restrict__ A2, const ushort_t* __restrict__ B2,
    const float* __restrict__ bias, float* __restrict__ Cf,
    ushort_t* __restrict__ Cb, int M, int N, int K)
{
    __shared__ ushort_t As[64][72];
    __shared__ ushort_t Bs[64][72];
    const int tid = threadIdx.x;
    const int l = tid & 63, w = tid >> 6;
    const int m0 = blockIdx.y * 64, n0 = blockIdx.x * 64;

    f32x4 acc[4];
#pragma unroll
    for (int m = 0; m < 4; ++m) acc[m] = (f32x4){0.f, 0.f, 0.f, 0.f};

    const int npass = DUAL ? 2 : 1;
    for (int pass = 0; pass < npass; ++pass) {
        const ushort_t* __restrict__ A = (DUAL && pass) ? A2 : A1;
        const ushort_t* __restrict__ B = (DUAL && pass) ? B2 : B1;
        for (int k0 = 0; k0 < K; k0 += 64) {
#pragma unroll
            for (int i = 0; i < 2; ++i) {
                int cid = tid + 256 * i;
                int row = cid >> 3, col = (cid & 7) * 8;
                *(uint4*)&As[row][col] = *(const uint4*)&A[(size_t)(m0 + row) * K + k0 + col];
                *(uint4*)&Bs[row][col] = *(const uint4*)&B[(size_t)(n0 + row) * K + k0 + col];
            }
            __syncthreads();
#pragma unroll
            for (int kk = 0; kk < 64; kk += 32) {
                bf16x8 b = *(const bf16x8*)&Bs[16 * w + (l & 15)][kk + (l >> 4) * 8];
#pragma unroll
                for (int m = 0; m < 4; ++m) {
                    bf16x8 a = *(const bf16x8*)&As[16 * m + (l & 15)][kk + (l >> 4) * 8];
                    acc[m] = __builtin_amdgcn_mfma_f32_16x16x32_bf16(a, b, acc[m], 0, 0, 0);
                }
            }
            __syncthreads();
        }
    }

#pragma unroll
    for (int m = 0; m < 4; ++m) {
#pragma unroll
        for (int r = 0; r < 4; ++r) {
            int row = m0 + 16 * m + (l >> 4) * 4 + r;
            int col = n0 + 16 * w + (l & 15);
            float v = acc[m][r];
            if (HAS_BIAS) v += bias[col];
            if (RELU) v = fmaxf(v, 0.f);
            if (OUTBF) Cb[(size_t)row * N + col] = f2bf(v);
            else       Cf[(size_t)row * N + col] = v;
        }
    }
}

// ---------------------------------------------------------------------------
// LSTM step t (t>=1), swapped-operand, 128-node x 64-dim tile.
//   gates^T[gate-dim][node] = whh @ h_prev^T via MFMA.
// 256 thr / 4 waves; wave w owns dims [d0+16w, d0+16w+16); NT=8 node tiles
// -> each whh A-fragment feeds 8 MFMAs (2x round-8 ratio). K-loop software-
// pipelined: kc+1's A-fragments prefetched under kc's 32 MFMAs. P/c gathered
// in per-nt epilogue rounds (keeps K-loop VGPR peak ~220).
// C-layout: col=lane&15 -> node, row=(lane>>4)*4+r -> 4 consecutive gate-dims.
// grid = (NN/128, D/64).  LDS: (D=256) 66KB -> 2 blk/CU; (D=128) 34KB.
// ---------------------------------------------------------------------------
template<int D>
__global__ __launch_bounds__(256, 2) void lstm_step3(
    const ushort_t* __restrict__ h_prev, const ushort_t* __restrict__ whh,
    const ushort_t* __restrict__ P, const int* __restrict__ nbr,
    ushort_t* __restrict__ c, ushort_t* __restrict__ h_next, int t)
{
    constexpr int HP = D + 8;
    constexpr int KC = D / 32;
    constexpr int NT = 8;
    __shared__ ushort_t As[128][HP];

    const int tid = threadIdx.x;
    const int l = tid & 63, w = tid >> 6;
    const int lr = l & 15, lg = l >> 4;
    const int m0 = blockIdx.x * 128;
    const int d0 = blockIdx.y * 64;
    const int dd = d0 + w * 16 + lg * 4;     // this lane's 4 out-dims

    // stage h tile (128 x D, coalesced 16B chunks)
    constexpr int CH = 128 * D / 8;
#pragma unroll
    for (int cid = tid; cid < CH; cid += 256) {
        int row = cid / (D / 8), cc = (cid % (D / 8)) * 8;
        *(uint4*)&As[row][cc] = *(const uint4*)&h_prev[(size_t)(m0 + row) * D + cc];
    }

    f32x4 acc[4][NT];
#pragma unroll
    for (int g = 0; g < 4; ++g)
#pragma unroll
        for (int nt = 0; nt < NT; ++nt) acc[g][nt] = (f32x4){0.f, 0.f, 0.f, 0.f};

    __syncthreads();   // As ready

    // K-loop, software-pipelined on the whh (L2) fragments
    const ushort_t* __restrict__ wbase = &whh[(size_t)(d0 + w * 16 + lr) * D + lg * 8];
    bf16x8 a_cur[4], a_nxt[4];
#pragma unroll
    for (int g = 0; g < 4; ++g)
        a_cur[g] = *(const bf16x8*)&wbase[(size_t)g * D * D];

#pragma unroll
    for (int kc = 0; kc < KC; ++kc) {
        if (kc + 1 < KC) {
#pragma unroll
            for (int g = 0; g < 4; ++g)
                a_nxt[g] = *(const bf16x8*)&wbase[(size_t)g * D * D + (kc + 1) * 32];
        }
        bf16x8 b[NT];
#pragma unroll
        for (int nt = 0; nt < NT; ++nt)
            b[nt] = *(const bf16x8*)&As[nt * 16 + lr][kc * 32 + lg * 8];
#pragma unroll
        for (int g = 0; g < 4; ++g)
#pragma unroll
            for (int nt = 0; nt < NT; ++nt)
                acc[g][nt] = __builtin_amdgcn_mfma_f32_16x16x32_bf16(
                    a_cur[g], b[nt], acc[g][nt], 0, 0, 0);
#pragma unroll
        for (int g = 0; g < 4; ++g) a_cur[g] = a_nxt[g];
    }

    // epilogue: per node-tile, gather P (8B per gate) + c, cell update, write
#pragma unroll
    for (int nt = 0; nt < NT; ++nt) {
        const int node = m0 + nt * 16 + lr;
        const int j = nbr[(size_t)node * DEG_ + t];
        const size_t base = (size_t)j * (4 * D) + dd;
        us4 pg[4];
#pragma unroll
        for (int g = 0; g < 4; ++g)
            pg[g] = *(const us4*)&P[base + g * D];
        const size_t ci = (size_t)node * D + dd;
        us4 cold = *(const us4*)&c[ci];

        us4 cnew, hnew;
#pragma unroll
        for (int r = 0; r < 4; ++r) {
            float gi = acc[0][nt][r] + bf2f(pg[0][r]);
            float gf = acc[1][nt][r] + bf2f(pg[1][r]);
            float gg = acc[2][nt][r] + bf2f(pg[2][r]);
            float go = acc[3][nt][r] + bf2f(pg[3][r]);
            float cn = sigf(gf) * bf2f(cold[r]) + sigf(gi) * tanhf_(gg);
            cnew[r] = f2bf(cn);
            hnew[r] = f2bf(sigf(go) * tanhf_(cn));
        }
        *(us4*)&c[ci] = cnew;
        *(us4*)&h_next[ci] = hnew;
    }
}

// ---------------------------------------------------------------------------
// Step t=0: h_prev = c_prev = 0 -> gates are just gathered P rows.
// ---------------------------------------------------------------------------
template<int D>
__global__ __launch_bounds__(256) void cell_first(
    const ushort_t* __restrict__ P, const int* __restrict__ nbr,
    ushort_t* __restrict__ c, ushort_t* __restrict__ h_out)
{
    int idx = blockIdx.x * 256 + threadIdx.x;  // n*D + d
    int n = idx / D, d = idx % D;
    int j = nbr[n * DEG_];
    size_t base = (size_t)j * (4 * D);
    float gi = bf2f(P[base + d]);
    float gg = bf2f(P[base + 2 * D + d]);
    float go = bf2f(P[base + 3 * D + d]);
    float cn = sigf(gi) * tanhf_(gg);
    c[idx] = f2bf(cn);
    h_out[idx] = f2bf(sigf(go) * tanhf_(cn));
}

// ---------------------------------------------------------------------------
__global__ void graph_counts(const int* __restrict__ n2g, int* __restrict__ cnt)
{
    __shared__ int lb[G_ + 1];
    int g = threadIdx.x;
    if (g <= G_) {
        int lo = 0, hi = NN_;
        while (lo < hi) {
            int mid = (lo + hi) >> 1;
            if (n2g[mid] < g) lo = mid + 1; else hi = mid;
        }
        lb[g] = lo;
    }
    __syncthreads();
    if (g < G_) cnt[g] = lb[g + 1] - lb[g];
}

// 64-node chunks -> 512 blocks.
__global__ __launch_bounds__(256) void seg_sum(
    const float* __restrict__ X, const int* __restrict__ n2g,
    float* __restrict__ gsum)
{
    int d = threadIdx.x;
    int n_start = blockIdx.x * 64;
    int cur = n2g[n_start];
    float acc = 0.f;
    for (int n = n_start; n < n_start + 64; ++n) {
        int g = n2g[n];
        if (g != cur) {
            atomicAdd(&gsum[cur * D2_ + d], acc);
            acc = 0.f;
            cur = g;
        }
        acc += X[(size_t)n * D2_ + d];
    }
    atomicAdd(&gsum[cur * D2_ + d], acc);
}

__global__ __launch_bounds__(128) void head_kernel(
    const float* __restrict__ gsum, const int* __restrict__ cnt,
    const float* __restrict__ w_mu, const float* __restrict__ b_mu,
    const float* __restrict__ w_sig, const float* __restrict__ b_sig,
    float* __restrict__ out)
{
    __shared__ float x[D2_];
    int g = blockIdx.x, j = threadIdx.x;
    float inv = 1.f / fmaxf((float)cnt[g], 1.f);
    x[j] = gsum[g * D2_ + j] * inv;
    x[j + 128] = gsum[g * D2_ + 128 + j] * inv;
    __syncthreads();
    float mu = b_mu[j], sg = b_sig[j];
    for (int k = 0; k < D2_; ++k) {
        float xv = x[k];
        mu += xv * w_mu[k * DREP_ + j];
        sg += xv * w_sig[k * DREP_ + j];
    }
    out[g * DREP_ + j] = mu;
    out[G_ * DREP_ + g * DREP_ + j] = sg;
}

// ---------------------------------------------------------------------------
extern "C" void kernel_launch(void* const* d_in, const int* in_sizes, int n_in,
                              void* d_out, int out_size, void* d_ws, size_t ws_size,
                              hipStream_t stream)
{
    const float* in_feat   = (const float*)d_in[0];
    const int*   neighbors = (const int*)d_in[1];
    const int*   node2graph= (const int*)d_in[2];
    const float* w_ih1     = (const float*)d_in[3];
    const float* w_hh1     = (const float*)d_in[4];
    const float* b_lstm1   = (const float*)d_in[5];
    const float* w_self1   = (const float*)d_in[6];
    const float* w_neigh1  = (const float*)d_in[7];
    const float* b1        = (const float*)d_in[8];
    const float* w_ih2     = (const float*)d_in[9];
    const float* w_hh2     = (const float*)d_in[10];
    const float* b_lstm2   = (const float*)d_in[11];
    const float* w_self2   = (const float*)d_in[12];
    const float* w_neigh2  = (const float*)d_in[13];
    const float* b2        = (const float*)d_in[14];
    const float* w_mu      = (const float*)d_in[15];
    const float* b_mu      = (const float*)d_in[16];
    const float* w_sigma   = (const float*)d_in[17];
    const float* b_sigma   = (const float*)d_in[18];

    void *pF1, *pHF, *pHA, *pHB, *pC, *pP, *pOH;
    void *pWI1, *pWH1, *pWS1, *pWN1, *pWI2, *pWH2, *pWS2, *pWN2, *pGS, *pGC;
    hipGetSymbolAddress(&pF1, HIP_SYMBOL(g_feat1));
    hipGetSymbolAddress(&pHF, HIP_SYMBOL(g_hfeat));
    hipGetSymbolAddress(&pHA, HIP_SYMBOL(g_hA));
    hipGetSymbolAddress(&pHB, HIP_SYMBOL(g_hB));
    hipGetSymbolAddress(&pC,  HIP_SYMBOL(g_c));
    hipGetSymbolAddress(&pP,  HIP_SYMBOL(g_P));
    hipGetSymbolAddress(&pOH, HIP_SYMBOL(g_outh));
    hipGetSymbolAddress(&pWI1, HIP_SYMBOL(g_wih1));
    hipGetSymbolAddress(&pWH1, HIP_SYMBOL(g_whh1));
    hipGetSymbolAddress(&pWS1, HIP_SYMBOL(g_wself1));
    hipGetSymbolAddress(&pWN1, HIP_SYMBOL(g_wneigh1));
    hipGetSymbolAddress(&pWI2, HIP_SYMBOL(g_wih2));
    hipGetSymbolAddress(&pWH2, HIP_SYMBOL(g_whh2));
    hipGetSymbolAddress(&pWS2, HIP_SYMBOL(g_wself2));
    hipGetSymbolAddress(&pWN2, HIP_SYMBOL(g_wneigh2));
    hipGetSymbolAddress(&pGS, HIP_SYMBOL(g_gsum));
    hipGetSymbolAddress(&pGC, HIP_SYMBOL(g_gcnt));

    ushort_t* feat1 = (ushort_t*)pF1;
    ushort_t* hfeat = (ushort_t*)pHF;
    ushort_t* hA    = (ushort_t*)pHA;
    ushort_t* hB    = (ushort_t*)pHB;
    ushort_t* c     = (ushort_t*)pC;
    ushort_t* P     = (ushort_t*)pP;
    float*    outh  = (float*)pOH;
    ushort_t* wih1  = (ushort_t*)pWI1;
    ushort_t* whh1  = (ushort_t*)pWH1;
    ushort_t* wself1= (ushort_t*)pWS1;
    ushort_t* wneigh1=(ushort_t*)pWN1;
    ushort_t* wih2  = (ushort_t*)pWI2;
    ushort_t* whh2  = (ushort_t*)pWH2;
    ushort_t* wself2= (ushort_t*)pWS2;
    ushort_t* wneigh2=(ushort_t*)pWN2;
    float*    gsum  = (float*)pGS;
    int*      gcnt  = (int*)pGC;

    // ---- Conversions ----
    cvt_bf16<<<(NN_ * D1_ + 255) / 256, 256, 0, stream>>>(in_feat, feat1, NN_ * D1_);
    cvt_bf16<<<(512 * 128 + 255) / 256, 256, 0, stream>>>(w_ih1, wih1, 512 * 128);
    cvt_bf16<<<(512 * 128 + 255) / 256, 256, 0, stream>>>(w_hh1, whh1, 512 * 128);
    cvt_bf16_T<<<(128 * 256 + 255) / 256, 256, 0, stream>>>(w_self1, wself1, 128, 256);
    cvt_bf16_T<<<(128 * 256 + 255) / 256, 256, 0, stream>>>(w_neigh1, wneigh1, 128, 256);
    cvt_bf16<<<(1024 * 256 + 255) / 256, 256, 0, stream>>>(w_ih2, wih2, 1024 * 256);
    cvt_bf16<<<(1024 * 256 + 255) / 256, 256, 0, stream>>>(w_hh2, whh2, 1024 * 256);
    cvt_bf16_T<<<(256 * 256 + 255) / 256, 256, 0, stream>>>(w_self2, wself2, 256, 256);
    cvt_bf16_T<<<(256 * 256 + 255) / 256, 256, 0, stream>>>(w_neigh2, wneigh2, 256, 256);

    // ---- Layer 1 ----
    // P1 = feat1 @ wih1^T + b_lstm1   [NN,512] -> bf16
    gemm_mfma<false, true, false, true>
        <<<dim3(512 / 64, NN_ / 64), 256, 0, stream>>>(
            feat1, wih1, nullptr, nullptr, b_lstm1, nullptr, P, NN_, 512, D1_);

    cell_first<D1_><<<(NN_ * D1_) / 256, 256, 0, stream>>>(P, neighbors, c, hA);
    for (int t = 1; t < DEG_; ++t) {
        const ushort_t* hp = (t & 1) ? hA : hB;
        ushort_t*       hn = (t & 1) ? hB : hA;
        lstm_step3<D1_><<<dim3(NN_ / 128, D1_ / 64), 256, 0, stream>>>(
            hp, whh1, P, neighbors, c, hn, t);
    }
    // h final in hB (t=15 odd)

    // hfeat = relu(feat1@wself1^T + hB@wneigh1^T + b1) -> bf16 [NN,256]
    gemm_mfma<true, true, true, true>
        <<<dim3(256 / 64, NN_ / 64), 256, 0, stream>>>(
            feat1, wself1, hB, wneigh1, b1, nullptr, hfeat, NN_, D2_, D1_);

    // ---- Layer 2 ----
    gemm_mfma<false, true, false, true>
        <<<dim3(1024 / 64, NN_ / 64), 256, 0, stream>>>(
            hfeat, wih2, nullptr, nullptr, b_lstm2, nullptr, P, NN_, 1024, D2_);

    cell_first<D2_><<<(NN_ * D2_) / 256, 256, 0, stream>>>(P, neighbors, c, hA);
    for (int t = 1; t < DEG_; ++t) {
        const ushort_t* hp = (t & 1) ? hA : hB;
        ushort_t*       hn = (t & 1) ? hB : hA;
        lstm_step3<D2_><<<dim3(NN_ / 128, D2_ / 64), 256, 0, stream>>>(
            hp, whh2, P, neighbors, c, hn, t);
    }

    // outh = hfeat@wself2^T + hB@wneigh2^T + b2   [NN,256] fp32
    gemm_mfma<true, true, false, false>
        <<<dim3(256 / 64, NN_ / 64), 256, 0, stream>>>(
            hfeat, wself2, hB, wneigh2, b2, outh, nullptr, NN_, D2_, D2_);

    // ---- Readout ----
    hipMemsetAsync(gsum, 0, (size_t)G_ * D2_ * sizeof(float), stream);
    graph_counts<<<1, 128, 0, stream>>>(node2graph, gcnt);
    seg_sum<<<NN_ / 64, 256, 0, stream>>>(outh, node2graph, gsum);
    head_kernel<<<G_, 128, 0, stream>>>(gsum, gcnt, w_mu, b_mu, w_sigma, b_sigma,
                                        (float*)d_out);
}